// Round 10
// baseline (1422.580 us; speedup 1.0000x reference)
//
#include <hip/hip_runtime.h>
#include <stdint.h>

#define DEV static __device__ __forceinline__

typedef __attribute__((ext_vector_type(8))) uint16_t u16x8;
typedef __attribute__((ext_vector_type(4))) uint16_t u16x4;
typedef __attribute__((ext_vector_type(4))) uint32_t u32x4;
typedef __attribute__((ext_vector_type(4))) float    f32x4;
typedef __attribute__((ext_vector_type(8))) __bf16   bf16x8;

typedef __attribute__((address_space(3))) void lds_void;
typedef __attribute__((address_space(1))) void gbl_void;

DEV float bf2f(uint16_t u){
  union { uint32_t i; float f; } v; v.i = ((uint32_t)u) << 16; return v.f;
}
DEV uint16_t f2bf(float f){ return __builtin_bit_cast(uint16_t, (__bf16)f); }
DEV f32x4 mfma16(u16x8 a, u16x8 b, f32x4 c){
  return __builtin_amdgcn_mfma_f32_16x16x32_bf16(
      __builtin_bit_cast(bf16x8, a), __builtin_bit_cast(bf16x8, b), c, 0, 0, 0);
}
DEV uint32_t cvt_pk_bf16(float lo, float hi){
  uint32_t r;
  asm("v_cvt_pk_bf16_f32 %0, %1, %2" : "=v"(r) : "v"(lo), "v"(hi));
  return r;
}

// ---------------------------------------------------------------------------
// fp32 -> bf16 elementwise convert, 8 elems/thread.
// ---------------------------------------------------------------------------
__global__ __launch_bounds__(256)
void te_cvt(const float* __restrict__ in, uint16_t* __restrict__ out)
{
  const size_t i = ((size_t)blockIdx.x * 256 + threadIdx.x) * 8;
  f32x4 a = *(const f32x4*)(in + i);
  f32x4 b = *(const f32x4*)(in + i + 4);
  u16x8 o;
#pragma unroll
  for (int e = 0; e < 4; e++) {
    o[e]     = f2bf(a[e]);
    o[e + 4] = f2bf(b[e]);
  }
  *(u16x8*)(out + i) = o;
}

// ---------------------------------------------------------------------------
// m97-structure 128x128 GEMM (round-7 proven, 818 TF on qkv):
// out[M,N] = A[M,K](lda) @ W[N,K]^T + bias. 256 thr (2x2 waves), BK=64,
// dual global_load_lds w=16, T2 chunk-XOR swizzle, setprio on MFMA clusters.
// Used for the qkv GEMM (N=3072): ~2 blocks/CU gives cross-block overlap
// at the barrier drain, which beats the 512-thr lockstep variant there.
// ---------------------------------------------------------------------------
__global__ __launch_bounds__(256)
void te_gemm_bb(const uint16_t* __restrict__ A, int lda,
                const uint16_t* __restrict__ W, const float* __restrict__ bias,
                uint16_t* __restrict__ outB, int M, int N, int K)
{
  __shared__ uint16_t la[128 * 64];
  __shared__ uint16_t lb[128 * 64];
  const int tid = threadIdx.x;
  const int w = tid >> 6, l = tid & 63;
  const int lr = l & 15, lg = l >> 4;
  const int tm = blockIdx.y * 128, tn = blockIdx.x * 128;
  const int srow = l >> 3;
  const int scol = ((l & 7) ^ srow) * 8;           // pre-swizzled source chunk
  const int wr = (w >> 1) * 64, wc = (w & 1) * 64;

  f32x4 acc[4][4] = {};

  for (int k0 = 0; k0 < K; k0 += 64) {
#pragma unroll
    for (int c = 0; c < 4; c++) {
      const int rb = (c * 4 + w) * 8;
      const uint16_t* ga = A + (size_t)(tm + rb + srow) * lda + (k0 + scol);
      __builtin_amdgcn_global_load_lds((gbl_void*)(uintptr_t)ga,
                                       (lds_void*)(la + rb * 64), 16, 0, 0);
      const uint16_t* gw = W + (size_t)(tn + rb + srow) * K + (k0 + scol);
      __builtin_amdgcn_global_load_lds((gbl_void*)(uintptr_t)gw,
                                       (lds_void*)(lb + rb * 64), 16, 0, 0);
    }
    __syncthreads();
#pragma unroll
    for (int kk = 0; kk < 2; kk++) {
      u16x8 af[4], bfr[4];
#pragma unroll
      for (int i = 0; i < 4; i++) {
        const int row = wr + i * 16 + lr;
        af[i] = *(const u16x8*)&la[row * 64 + (((kk * 4 + lg) ^ (lr & 7)) << 3)];
      }
#pragma unroll
      for (int j = 0; j < 4; j++) {
        const int row = wc + j * 16 + lr;
        bfr[j] = *(const u16x8*)&lb[row * 64 + (((kk * 4 + lg) ^ (lr & 7)) << 3)];
      }
      __builtin_amdgcn_s_setprio(1);
#pragma unroll
      for (int i = 0; i < 4; i++)
#pragma unroll
        for (int j = 0; j < 4; j++)
          acc[i][j] = mfma16(af[i], bfr[j], acc[i][j]);
      __builtin_amdgcn_s_setprio(0);
    }
    __syncthreads();
  }

  float bv[4];
#pragma unroll
  for (int j = 0; j < 4; j++) bv[j] = bias[tn + wc + j * 16 + lr];
#pragma unroll
  for (int i = 0; i < 4; i++)
#pragma unroll
    for (int j = 0; j < 4; j++)
#pragma unroll
      for (int r = 0; r < 4; r++) {
        const int row = tm + wr + i * 16 + lg * 4 + r;
        const int col = tn + wc + j * 16 + lr;
        float v = acc[i][j][r] + bv[j];
        outB[(size_t)row * N + col] = f2bf(v);
      }
}

// ---------------------------------------------------------------------------
// Deep-pipelined GEMM v2 (kept for N=1024 GEMMs: 256-block grids fill CUs):
// 256x128 block, BK=64, 512 thr = 8 waves (4M x 2N, wave tile 64x64).
// Triple-buffered LDS (144 KB), 2-deep prefetch, counted vmcnt(12/6/0),
// 2 raw s_barriers per K-tile, T2 chunk-XOR swizzle, bijective XCD swizzle.
// MODE 0: bias -> bf16.  MODE 2: bias + GELU(tanh) -> bf16.
// ---------------------------------------------------------------------------
template<int MODE>
__global__ __launch_bounds__(512)
void te_gemm256(const uint16_t* __restrict__ A, int lda,
                const uint16_t* __restrict__ Wm, const float* __restrict__ bias,
                uint16_t* __restrict__ outB, int N, int K)
{
  constexpr int SZA = 256 * 64;           // A tile elems
  constexpr int SZB = 128 * 64;           // B tile elems
  __shared__ uint16_t lds[3 * (SZA + SZB)];   // 144 KiB

  const int tid = threadIdx.x;
  const int w = tid >> 6, l = tid & 63;
  const int lr = l & 15, lg = l >> 4;
  const int wr = w >> 1, wc = w & 1;      // 4M x 2N wave grid, 64x64 tiles
  const int srow = l >> 3, chunk = l & 7;

  // bijective XCD swizzle on flat block id (gridDim.x % 8 == 0)
  const int nb = gridDim.x;
  const int bid = blockIdx.x;
  const int lid = (bid & 7) * (nb >> 3) + (bid >> 3);
  const int nx = N >> 7;
  const int tm = (lid / nx) << 8;
  const int tn = (lid % nx) << 7;

  const int rw = w * 8 + srow;            // 0..63 stage row within 64-row group
  const int sc = (chunk ^ srow) << 3;     // pre-swizzled source col chunk

  auto stage = [&](int kt, int p) {
    const int k0 = kt << 6;
    uint16_t* bufA = lds + p * (SZA + SZB);
    uint16_t* bufB = bufA + SZA;
#pragma unroll
    for (int c = 0; c < 4; c++) {
      const uint16_t* ga = A + (size_t)(tm + c * 64 + rw) * lda + (k0 + sc);
      __builtin_amdgcn_global_load_lds((gbl_void*)(uintptr_t)ga,
          (lds_void*)(bufA + (c * 64 + w * 8) * 64), 16, 0, 0);
    }
#pragma unroll
    for (int c = 0; c < 2; c++) {
      const uint16_t* gw = Wm + (size_t)(tn + c * 64 + rw) * K + (k0 + sc);
      __builtin_amdgcn_global_load_lds((gbl_void*)(uintptr_t)gw,
          (lds_void*)(bufB + (c * 64 + w * 8) * 64), 16, 0, 0);
    }
  };

  f32x4 acc[4][4] = {};
  const int nt = K >> 6;

  stage(0, 0);
  stage(1, 1);
  for (int t = 0; t < nt; ++t) {
    const int cur = t % 3;
    uint16_t* bufA = lds + cur * (SZA + SZB);
    uint16_t* bufB = bufA + SZA;

    asm volatile("" ::: "memory");
    if (t + 2 < nt) {
      stage(t + 2, (t + 2) % 3);
      asm volatile("s_waitcnt vmcnt(12)" ::: "memory");   // tile t landed
    } else if (t + 1 < nt) {
      asm volatile("s_waitcnt vmcnt(6)" ::: "memory");
    } else {
      asm volatile("s_waitcnt vmcnt(0)" ::: "memory");
    }
    __builtin_amdgcn_s_barrier();         // tile t visible to all waves

#pragma unroll
    for (int kk = 0; kk < 2; kk++) {
      u16x8 af[4], bfr[2];
#pragma unroll
      for (int i = 0; i < 4; i++) {
        const int row = wr * 64 + i * 16 + lr;
        af[i] = *(const u16x8*)&bufA[row * 64 + (((kk * 4 + lg) ^ (lr & 7)) << 3)];
      }
#pragma unroll
      for (int j = 0; j < 2; j++) {
        const int row = wc * 64 + j * 16 + lr;
        bfr[j] = *(const u16x8*)&bufB[row * 64 + (((kk * 4 + lg) ^ (lr & 7)) << 3)];
      }
      u16x8 bfr2[2];
#pragma unroll
      for (int j = 0; j < 2; j++) {
        const int row = wc * 64 + (j + 2) * 16 + lr;
        bfr2[j] = *(const u16x8*)&bufB[row * 64 + (((kk * 4 + lg) ^ (lr & 7)) << 3)];
      }
      __builtin_amdgcn_s_setprio(1);
#pragma unroll
      for (int i = 0; i < 4; i++) {
        acc[i][0] = mfma16(af[i], bfr[0],  acc[i][0]);
        acc[i][1] = mfma16(af[i], bfr[1],  acc[i][1]);
        acc[i][2] = mfma16(af[i], bfr2[0], acc[i][2]);
        acc[i][3] = mfma16(af[i], bfr2[1], acc[i][3]);
      }
      __builtin_amdgcn_s_setprio(0);
    }
    __builtin_amdgcn_s_barrier();         // reads of buf cur complete
  }

  // epilogue
  float bv[4];
#pragma unroll
  for (int j = 0; j < 4; j++) bv[j] = bias[tn + wc * 64 + j * 16 + lr];
#pragma unroll
  for (int i = 0; i < 4; i++)
#pragma unroll
    for (int j = 0; j < 4; j++)
#pragma unroll
      for (int r = 0; r < 4; r++) {
        const int row = tm + wr * 64 + i * 16 + lg * 4 + r;
        const int col = tn + wc * 64 + j * 16 + lr;
        float v = acc[i][j][r] + bv[j];
        if (MODE == 2) {
          const float u = 0.7978845608028654f * v * (1.0f + 0.044715f * v * v);
          const float t = 1.0f - 2.0f / (__expf(2.0f * u) + 1.0f);
          v = 0.5f * v * (1.0f + t);
        }
        outB[(size_t)row * N + col] = f2bf(v);
      }
}

// ---------------------------------------------------------------------------
// softmax + pack macro (per q-group), S^T layout: lane lr owns q-row iQ.
// ---------------------------------------------------------------------------
#define SOFTMAX_PACK(S, MR, SDQ, ACC, IQ, P2)                                  \
  {                                                                            \
    const float f0 = (float)((IQ) - jt - lg * 4);                              \
    float mt = -1e30f;                                                         \
    _Pragma("unroll")                                                          \
    for (int n = 0; n < 4; n++) {                                              \
      const float fj = f0 - (float)(n * 16);                                   \
      _Pragma("unroll")                                                        \
      for (int r = 0; r < 4; r++) {                                            \
        const float v = fmaf(S[n][r], scl2e, -slope2e * fabsf(fj - (float)r)); \
        S[n][r] = v;                                                           \
        mt = fmaxf(mt, v);                                                     \
      }                                                                        \
    }                                                                          \
    mt = fmaxf(mt, __shfl_xor(mt, 16));                                        \
    mt = fmaxf(mt, __shfl_xor(mt, 32));                                        \
    if (!__all(mt <= MR)) {                                                    \
      const float mN = fmaxf(MR, mt);                                          \
      const float fq = exp2f(MR - mN);                                         \
      MR = mN;                                                                 \
      SDQ *= fq;                                                               \
      float fA[4];                                                             \
      _Pragma("unroll")                                                        \
      for (int r = 0; r < 4; r++) fA[r] = __shfl(fq, lg * 4 + r);              \
      _Pragma("unroll")                                                        \
      for (int n = 0; n < 4; n++)                                              \
        _Pragma("unroll")                                                      \
        for (int r = 0; r < 4; r++) ACC[n][r] *= fA[r];                        \
    }                                                                          \
    float rs = 0.0f;                                                           \
    _Pragma("unroll")                                                          \
    for (int n = 0; n < 4; n++)                                                \
      _Pragma("unroll")                                                        \
      for (int r = 0; r < 4; r++) {                                            \
        const float p = exp2f(S[n][r] - MR);                                   \
        S[n][r] = p;                                                           \
        rs += p;                                                               \
      }                                                                        \
    rs += __shfl_xor(rs, 16);                                                  \
    rs += __shfl_xor(rs, 32);                                                  \
    SDQ += rs;                                                                 \
    _Pragma("unroll")                                                          \
    for (int n = 0; n < 4; n++) {                                              \
      P2[n][0] = cvt_pk_bf16(S[n][0], S[n][1]);                                \
      P2[n][1] = cvt_pk_bf16(S[n][2], S[n][3]);                                \
    }                                                                          \
  }

// ---------------------------------------------------------------------------
// Fused attention v3: QBLK=128 (2 q-groups/block, staging amortized 2x).
// Swapped QK^T, exp2 domain, exact defer-max (diag-first), in-register P.
// qkv [B*T, 3072] bf16; grid (bh=256, qt=4). In-place q output.
// ---------------------------------------------------------------------------
__global__ __launch_bounds__(256)
void te_attn(uint16_t* __restrict__ qkv)
{
  __shared__ uint16_t kl[64 * 64];   // K[j][d] swizzled chunks
  __shared__ uint16_t vt[64 * 64];   // V^T[d][j] swizzled chunks
  const int tid = threadIdx.x;
  const int w = tid >> 6, l = tid & 63;
  const int lr = l & 15, lg = l >> 4;
  const int bh = blockIdx.x, qt = blockIdx.y;   // qt 0..3
  const int h = bh & 15, b = bh >> 4;

  const int iQ0 = qt * 128 + w * 16 + lr;       // group 0; group 1 = +64
  u16x8 qf[2][2];
#pragma unroll
  for (int g = 0; g < 2; g++) {
    const size_t qoff = ((size_t)(b * 512 + iQ0 + g * 64)) * 3072 + h * 64 + lg * 8;
    qf[g][0] = *(const u16x8*)&qkv[qoff];
    qf[g][1] = *(const u16x8*)&qkv[qoff + 32];
  }
  const float LOG2E = 1.4426950408889634f;
  const float scl2e = 0.125f * LOG2E;
  const float slope2e = exp2f(-0.5f * (float)(h + 1)) * LOG2E;

  const int sjb = tid >> 3;           // 0..31 (j within half-tile)
  const int sd0 = (tid & 7) * 8;      // d chunk start

  float mR0 = -1e30f, sdq0 = 0.0f, mR1 = -1e30f, sdq1 = 0.0f;
  f32x4 acc0[4] = {}, acc1[4] = {};

  // prologue: load first (diagonal-of-group-0) tile into regs
  u16x8 kreg[2], vreg[2];
  {
    const int jt0 = (qt * 2) * 64;
#pragma unroll
    for (int cc = 0; cc < 2; cc++) {
      const int j = sjb + cc * 32;
      const size_t rbase = ((size_t)(b * 512 + jt0 + j)) * 3072 + h * 64 + sd0;
      kreg[cc] = *(const u16x8*)&qkv[rbase + 1024];
      vreg[cc] = *(const u16x8*)&qkv[rbase + 2048];
    }
  }

  for (int step = 0; step < 8; step++) {
    const int jt = ((qt * 2 + step) & 7) * 64;
    // ---- write staged regs to LDS ----
#pragma unroll
    for (int cc = 0; cc < 2; cc++) {
      const int j = sjb + cc * 32;
      *(u16x8*)&kl[j * 64 + (((sd0 >> 3) ^ (j & 7)) << 3)] = kreg[cc];
      const int cV = (((j >> 3) ^ (sd0 >> 3)) << 3) + (j & 7);
#pragma unroll
      for (int e = 0; e < 8; e++) vt[(sd0 + e) * 64 + cV] = vreg[cc][e];
    }
    __syncthreads();
    // ---- issue next tile's global loads (hidden under compute) ----
    if (step < 7) {
      const int jtn = ((qt * 2 + step + 1) & 7) * 64;
#pragma unroll
      for (int cc = 0; cc < 2; cc++) {
        const int j = sjb + cc * 32;
        const size_t rbase = ((size_t)(b * 512 + jtn + j)) * 3072 + h * 64 + sd0;
        kreg[cc] = *(const u16x8*)&qkv[rbase + 1024];
        vreg[cc] = *(const u16x8*)&qkv[rbase + 2048];
      }
    }

    // ---- S^T = mfma(K, Q) for both q-groups (K-frags shared) ----
    f32x4 s0[4] = {}, s1[4] = {};
#pragma unroll
    for (int kk = 0; kk < 2; kk++) {
      u16x8 kf[4];
#pragma unroll
      for (int n = 0; n < 4; n++) {
        const int row = n * 16 + lr;
        kf[n] = *(const u16x8*)&kl[row * 64 + (((kk * 4 + lg) ^ (lr & 7)) << 3)];
      }
      __builtin_amdgcn_s_setprio(1);
#pragma unroll
      for (int n = 0; n < 4; n++) {
        s0[n] = mfma16(kf[n], qf[0][kk], s0[n]);
        s1[n] = mfma16(kf[n], qf[1][kk], s1[n]);
      }
      __builtin_amdgcn_s_setprio(0);
    }

    // ---- softmax + pack per group ----
    uint32_t P2a[4][2], P2b[4][2];
    SOFTMAX_PACK(s0, mR0, sdq0, acc0, iQ0,      P2a);
    SOFTMAX_PACK(s1, mR1, sdq1, acc1, iQ0 + 64, P2b);

    // ---- redistribute to A-frag layout + PV (V-frags shared) ----
#pragma unroll
    for (int kk = 0; kk < 2; kk++) {
      uint32_t pw0[4], pw1[4];
#pragma unroll
      for (int t = 0; t < 4; t++) {
        const int srcLane = lr + 16 * ((lg & 1) * 2 + (t >> 1));
        const uint32_t a0 = __shfl(P2a[2 * kk + 0][t & 1], srcLane);
        const uint32_t b0 = __shfl(P2a[2 * kk + 1][t & 1], srcLane);
        pw0[t] = (lg >> 1) ? b0 : a0;
        const uint32_t a1 = __shfl(P2b[2 * kk + 0][t & 1], srcLane);
        const uint32_t b1 = __shfl(P2b[2 * kk + 1][t & 1], srcLane);
        pw1[t] = (lg >> 1) ? b1 : a1;
      }
      u32x4 q0 = { pw0[0], pw0[1], pw0[2], pw0[3] };
      u32x4 q1 = { pw1[0], pw1[1], pw1[2], pw1[3] };
      u16x8 pf0 = __builtin_bit_cast(u16x8, q0);
      u16x8 pf1 = __builtin_bit_cast(u16x8, q1);
      u16x8 vf[4];
#pragma unroll
      for (int n = 0; n < 4; n++) {
        const int row = n * 16 + lr;
        vf[n] = *(const u16x8*)&vt[row * 64 + ((((kk * 4 + lg) ^ (2 * n + (lr >> 3))) & 7) << 3)];
      }
      __builtin_amdgcn_s_setprio(1);
#pragma unroll
      for (int n = 0; n < 4; n++) {
        acc0[n] = mfma16(pf0, vf[n], acc0[n]);
        acc1[n] = mfma16(pf1, vf[n], acc1[n]);
      }
      __builtin_amdgcn_s_setprio(0);
    }
    __syncthreads();
  }

  // ---- epilogue: O[i][d] for both groups ----
  {
    float sdA[4];
#pragma unroll
    for (int r = 0; r < 4; r++) sdA[r] = 1.0f / __shfl(sdq0, lg * 4 + r);
#pragma unroll
    for (int n = 0; n < 4; n++)
#pragma unroll
      for (int r = 0; r < 4; r++) {
        const int i = qt * 128 + w * 16 + lg * 4 + r;
        const int d = h * 64 + n * 16 + lr;
        qkv[((size_t)(b * 512 + i)) * 3072 + d] = f2bf(acc0[n][r] * sdA[r]);
      }
  }
  {
    float sdA[4];
#pragma unroll
    for (int r = 0; r < 4; r++) sdA[r] = 1.0f / __shfl(sdq1, lg * 4 + r);
#pragma unroll
    for (int n = 0; n < 4; n++)
#pragma unroll
      for (int r = 0; r < 4; r++) {
        const int i = qt * 128 + 64 + w * 16 + lg * 4 + r;
        const int d = h * 64 + n * 16 + lr;
        qkv[((size_t)(b * 512 + i)) * 3072 + d] = f2bf(acc1[n][r] * sdA[r]);
      }
  }
}

// ---------------------------------------------------------------------------
// LN (bf16 residual): x = h(bf16) + delta(bf16) in f32; y = LN(x)*w + b.
// FINAL=0: writes hout (bf16, aliases h).  FINAL=1: writes fout (f32 d_out).
// ---------------------------------------------------------------------------
template<int FINAL>
__global__ __launch_bounds__(256)
void te_ln(const uint16_t* __restrict__ h, const uint16_t* __restrict__ delta,
           const float* __restrict__ w, const float* __restrict__ b,
           uint16_t* __restrict__ hout, float* __restrict__ fout)
{
  const int row = blockIdx.x, t = threadIdx.x;
  const size_t base = (size_t)row * 1024 + t * 4;
  u16x4 hv = *(const u16x4*)&h[base];
  u16x4 dv = *(const u16x4*)&delta[base];
  float x[4];
#pragma unroll
  for (int i = 0; i < 4; i++) x[i] = bf2f(hv[i]) + bf2f(dv[i]);
  float s = x[0] + x[1] + x[2] + x[3];
  float ss = x[0]*x[0] + x[1]*x[1] + x[2]*x[2] + x[3]*x[3];
#pragma unroll
  for (int msk = 32; msk >= 1; msk >>= 1) {
    s  += __shfl_xor(s, msk);
    ss += __shfl_xor(ss, msk);
  }
  __shared__ float rs[4], rq[4];
  const int wv = t >> 6;
  if ((t & 63) == 0) { rs[wv] = s; rq[wv] = ss; }
  __syncthreads();
  s  = rs[0] + rs[1] + rs[2] + rs[3];
  ss = rq[0] + rq[1] + rq[2] + rq[3];
  const float mean = s * (1.0f / 1024.0f);
  const float var  = ss * (1.0f / 1024.0f) - mean * mean;
  const float rstd = rsqrtf(var + 1e-5f);
  f32x4 wv4 = *(const f32x4*)&w[t * 4];
  f32x4 bv4 = *(const f32x4*)&b[t * 4];
  if (FINAL == 0) {
    u16x4 bo;
#pragma unroll
    for (int i = 0; i < 4; i++)
      bo[i] = f2bf((x[i] - mean) * rstd * wv4[i] + bv4[i]);
    *(u16x4*)&hout[base] = bo;
  } else {
    f32x4 yo;
#pragma unroll
    for (int i = 0; i < 4; i++)
      yo[i] = (x[i] - mean) * rstd * wv4[i] + bv4[i];
    *(f32x4*)&fout[base] = yo;
  }
}

// ---------------------------------------------------------------------------
extern "C" void kernel_launch(void* const* d_in, const int* in_sizes, int n_in,
                              void* d_out, int out_size, void* d_ws, size_t ws_size,
                              hipStream_t stream)
{
  (void)in_sizes; (void)n_in; (void)out_size; (void)ws_size;
  const float* x     = (const float*)d_in[0];
  const float* bn_w  = (const float*)d_in[1];
  const float* bn_b  = (const float*)d_in[2];
  const float* qkv_w = (const float*)d_in[3];
  const float* qkv_b = (const float*)d_in[4];
  const float* out_w = (const float*)d_in[5];
  const float* out_b = (const float*)d_in[6];
  const float* ln1_w = (const float*)d_in[7];
  const float* ln1_b = (const float*)d_in[8];
  const float* ln2_w = (const float*)d_in[9];
  const float* ln2_b = (const float*)d_in[10];
  const float* ff1_w = (const float*)d_in[11];
  const float* ff1_b = (const float*)d_in[12];
  const float* ff2_w = (const float*)d_in[13];
  const float* ff2_b = (const float*)d_in[14];

  char* ws = (char*)d_ws;
  uint16_t* h_bf    = (uint16_t*)ws;                      // 16 MiB @ 0
  uint16_t* qkvb    = (uint16_t*)(ws + (16u  << 20));     // 48 MiB @ 16
  uint16_t* scrA    = (uint16_t*)(ws + (64u  << 20));     // 16 MiB @ 64 (also x_bf)
  uint16_t* qkvw_bf = (uint16_t*)(ws + (80u  << 20));     // 36 MiB @ 80
  uint16_t* ff2w_bf = (uint16_t*)(ws + (116u << 20));     // 12 MiB @ 116
  uint16_t* bnw_bf  = (uint16_t*)(ws + (128u << 20));     //  2 MiB @ 128 (130 total)
  // d_out as scratch for weights that die before the final LN writes d_out:
  uint16_t* outw_bf = (uint16_t*)d_out;                   // 12 MiB @ 0
  uint16_t* ff1w_bf = (uint16_t*)((char*)d_out + (12u << 20)); // 12 MiB @ 12
  float*    outf    = (float*)d_out;                      // final fp32 output

  dim3 blk(256);
  dim3 blk512(512);

  // one-time fp32 -> bf16 conversions (weights + x)
  te_cvt<<<dim3(18874368 / 2048), blk, 0, stream>>>(qkv_w, qkvw_bf);
  te_cvt<<<dim3(6291456  / 2048), blk, 0, stream>>>(out_w, outw_bf);
  te_cvt<<<dim3(6291456  / 2048), blk, 0, stream>>>(ff1_w, ff1w_bf);
  te_cvt<<<dim3(6291456  / 2048), blk, 0, stream>>>(ff2_w, ff2w_bf);
  te_cvt<<<dim3(1048576  / 2048), blk, 0, stream>>>(bn_w,  bnw_bf);
  te_cvt<<<dim3(8388608  / 2048), blk, 0, stream>>>(x,     scrA);

  // bottleneck: h0 = x @ bn_w^T + bn_b  (bf16 residual)
  te_gemm256<0><<<dim3(256), blk512, 0, stream>>>(scrA, 1024, bnw_bf, bn_b,
                                                  h_bf, 1024, 1024);

  for (int l = 0; l < 6; l++) {
    te_gemm_bb<<<dim3(24, 64), blk, 0, stream>>>(
        h_bf, 1024, qkvw_bf + (size_t)l * 3072 * 1024, qkv_b + l * 3072,
        qkvb, 8192, 3072, 1024);
    te_attn<<<dim3(256, 4), blk, 0, stream>>>(qkvb);
    te_gemm256<0><<<dim3(256), blk512, 0, stream>>>(
        qkvb, 3072, outw_bf + (size_t)l * 1024 * 1024, out_b + l * 1024,
        scrA, 1024, 1024);
    te_ln<0><<<dim3(8192), blk, 0, stream>>>(h_bf, scrA, ln1_w + l * 1024, ln1_b + l * 1024,
                                             h_bf, nullptr);
    te_gemm256<2><<<dim3(256), blk512, 0, stream>>>(
        h_bf, 1024, ff1w_bf + (size_t)l * 1024 * 1024, ff1_b + l * 1024,
        scrA, 1024, 1024);
    te_gemm256<0><<<dim3(256), blk512, 0, stream>>>(
        scrA, 1024, ff2w_bf + (size_t)l * 1024 * 1024, ff2_b + l * 1024,
        qkvb, 1024, 1024);
    if (l == 5) {
      te_ln<1><<<dim3(8192), blk, 0, stream>>>(h_bf, qkvb, ln2_w + l * 1024, ln2_b + l * 1024,
                                               nullptr, outf);
    } else {
      te_ln<0><<<dim3(8192), blk, 0, stream>>>(h_bf, qkvb, ln2_w + l * 1024, ln2_b + l * 1024,
                                               h_bf, nullptr);
    }
  }
}

// Round 11
// 1372.731 us; speedup vs baseline: 1.0363x; 1.0363x over previous
//
#include <hip/hip_runtime.h>
#include <stdint.h>

#define DEV static __device__ __forceinline__

typedef __attribute__((ext_vector_type(8))) uint16_t u16x8;
typedef __attribute__((ext_vector_type(4))) uint16_t u16x4;
typedef __attribute__((ext_vector_type(4))) uint32_t u32x4;
typedef __attribute__((ext_vector_type(4))) float    f32x4;
typedef __attribute__((ext_vector_type(8))) __bf16   bf16x8;

typedef __attribute__((address_space(3))) void lds_void;
typedef __attribute__((address_space(1))) void gbl_void;

DEV float bf2f(uint16_t u){
  union { uint32_t i; float f; } v; v.i = ((uint32_t)u) << 16; return v.f;
}
DEV uint16_t f2bf(float f){ return __builtin_bit_cast(uint16_t, (__bf16)f); }
DEV f32x4 mfma16(u16x8 a, u16x8 b, f32x4 c){
  return __builtin_amdgcn_mfma_f32_16x16x32_bf16(
      __builtin_bit_cast(bf16x8, a), __builtin_bit_cast(bf16x8, b), c, 0, 0, 0);
}
DEV uint32_t cvt_pk_bf16(float lo, float hi){
  uint32_t r;
  asm("v_cvt_pk_bf16_f32 %0, %1, %2" : "=v"(r) : "v"(lo), "v"(hi));
  return r;
}

// ---------------------------------------------------------------------------
// Single merged fp32 -> bf16 convert for all weights + x (one launch).
// Segment boundaries are multiples of 2048*8 so each thread's 8-elem chunk
// stays within one segment. Total 47185920 elems -> 23040 blocks.
// ---------------------------------------------------------------------------
__global__ __launch_bounds__(256)
void te_cvt_all(const float* __restrict__ qkv_w, const float* __restrict__ out_w,
                const float* __restrict__ ff1_w, const float* __restrict__ ff2_w,
                const float* __restrict__ bn_w,  const float* __restrict__ x,
                uint16_t* __restrict__ qkvw_bf, uint16_t* __restrict__ outw_bf,
                uint16_t* __restrict__ ff1w_bf, uint16_t* __restrict__ ff2w_bf,
                uint16_t* __restrict__ bnw_bf,  uint16_t* __restrict__ x_bf)
{
  const size_t i = ((size_t)blockIdx.x * 256 + threadIdx.x) * 8;
  const float* src; uint16_t* dst; size_t off;
  if      (i < 18874368u) { src = qkv_w; dst = qkvw_bf; off = i; }
  else if (i < 25165824u) { src = out_w; dst = outw_bf; off = i - 18874368u; }
  else if (i < 31457280u) { src = ff1_w; dst = ff1w_bf; off = i - 25165824u; }
  else if (i < 37748736u) { src = ff2_w; dst = ff2w_bf; off = i - 31457280u; }
  else if (i < 38797312u) { src = bn_w;  dst = bnw_bf;  off = i - 37748736u; }
  else                    { src = x;     dst = x_bf;    off = i - 38797312u; }
  f32x4 a = *(const f32x4*)(src + off);
  f32x4 b = *(const f32x4*)(src + off + 4);
  u16x8 o;
#pragma unroll
  for (int e = 0; e < 4; e++) {
    o[e]     = f2bf(a[e]);
    o[e + 4] = f2bf(b[e]);
  }
  *(u16x8*)(dst + off) = o;
}

// ---------------------------------------------------------------------------
// Deep-pipelined GEMM v2 (r9 config, used for ALL GEMMs):
// 256x128 block, BK=64, 512 thr = 8 waves (4M x 2N, wave tile 64x64).
// Triple-buffered LDS (144 KB), 2-deep prefetch, counted vmcnt(12/6/0),
// 2 raw s_barriers per K-tile, T2 chunk-XOR swizzle, bijective XCD swizzle.
// MODE 0: bias -> bf16.  MODE 2: bias + GELU(tanh) -> bf16.
// ---------------------------------------------------------------------------
template<int MODE>
__global__ __launch_bounds__(512)
void te_gemm256(const uint16_t* __restrict__ A, int lda,
                const uint16_t* __restrict__ Wm, const float* __restrict__ bias,
                uint16_t* __restrict__ outB, int N, int K)
{
  constexpr int SZA = 256 * 64;           // A tile elems
  constexpr int SZB = 128 * 64;           // B tile elems
  __shared__ uint16_t lds[3 * (SZA + SZB)];   // 144 KiB

  const int tid = threadIdx.x;
  const int w = tid >> 6, l = tid & 63;
  const int lr = l & 15, lg = l >> 4;
  const int wr = w >> 1, wc = w & 1;      // 4M x 2N wave grid, 64x64 tiles
  const int srow = l >> 3, chunk = l & 7;

  // bijective XCD swizzle on flat block id (gridDim.x % 8 == 0)
  const int nb = gridDim.x;
  const int bid = blockIdx.x;
  const int lid = (bid & 7) * (nb >> 3) + (bid >> 3);
  const int nx = N >> 7;
  const int tm = (lid / nx) << 8;
  const int tn = (lid % nx) << 7;

  const int rw = w * 8 + srow;            // 0..63 stage row within 64-row group
  const int sc = (chunk ^ srow) << 3;     // pre-swizzled source col chunk

  auto stage = [&](int kt, int p) {
    const int k0 = kt << 6;
    uint16_t* bufA = lds + p * (SZA + SZB);
    uint16_t* bufB = bufA + SZA;
#pragma unroll
    for (int c = 0; c < 4; c++) {
      const uint16_t* ga = A + (size_t)(tm + c * 64 + rw) * lda + (k0 + sc);
      __builtin_amdgcn_global_load_lds((gbl_void*)(uintptr_t)ga,
          (lds_void*)(bufA + (c * 64 + w * 8) * 64), 16, 0, 0);
    }
#pragma unroll
    for (int c = 0; c < 2; c++) {
      const uint16_t* gw = Wm + (size_t)(tn + c * 64 + rw) * K + (k0 + sc);
      __builtin_amdgcn_global_load_lds((gbl_void*)(uintptr_t)gw,
          (lds_void*)(bufB + (c * 64 + w * 8) * 64), 16, 0, 0);
    }
  };

  f32x4 acc[4][4] = {};
  const int nt = K >> 6;

  stage(0, 0);
  stage(1, 1);
  for (int t = 0; t < nt; ++t) {
    const int cur = t % 3;
    uint16_t* bufA = lds + cur * (SZA + SZB);
    uint16_t* bufB = bufA + SZA;

    asm volatile("" ::: "memory");
    if (t + 2 < nt) {
      stage(t + 2, (t + 2) % 3);
      asm volatile("s_waitcnt vmcnt(12)" ::: "memory");   // tile t landed
    } else if (t + 1 < nt) {
      asm volatile("s_waitcnt vmcnt(6)" ::: "memory");
    } else {
      asm volatile("s_waitcnt vmcnt(0)" ::: "memory");
    }
    __builtin_amdgcn_s_barrier();         // tile t visible to all waves

#pragma unroll
    for (int kk = 0; kk < 2; kk++) {
      u16x8 af[4], bfr[2];
#pragma unroll
      for (int i = 0; i < 4; i++) {
        const int row = wr * 64 + i * 16 + lr;
        af[i] = *(const u16x8*)&bufA[row * 64 + (((kk * 4 + lg) ^ (lr & 7)) << 3)];
      }
#pragma unroll
      for (int j = 0; j < 2; j++) {
        const int row = wc * 64 + j * 16 + lr;
        bfr[j] = *(const u16x8*)&bufB[row * 64 + (((kk * 4 + lg) ^ (lr & 7)) << 3)];
      }
      u16x8 bfr2[2];
#pragma unroll
      for (int j = 0; j < 2; j++) {
        const int row = wc * 64 + (j + 2) * 16 + lr;
        bfr2[j] = *(const u16x8*)&bufB[row * 64 + (((kk * 4 + lg) ^ (lr & 7)) << 3)];
      }
      __builtin_amdgcn_s_setprio(1);
#pragma unroll
      for (int i = 0; i < 4; i++) {
        acc[i][0] = mfma16(af[i], bfr[0],  acc[i][0]);
        acc[i][1] = mfma16(af[i], bfr[1],  acc[i][1]);
        acc[i][2] = mfma16(af[i], bfr2[0], acc[i][2]);
        acc[i][3] = mfma16(af[i], bfr2[1], acc[i][3]);
      }
      __builtin_amdgcn_s_setprio(0);
    }
    __builtin_amdgcn_s_barrier();         // reads of buf cur complete
  }

  // epilogue
  float bv[4];
#pragma unroll
  for (int j = 0; j < 4; j++) bv[j] = bias[tn + wc * 64 + j * 16 + lr];
#pragma unroll
  for (int i = 0; i < 4; i++)
#pragma unroll
    for (int j = 0; j < 4; j++)
#pragma unroll
      for (int r = 0; r < 4; r++) {
        const int row = tm + wr * 64 + i * 16 + lg * 4 + r;
        const int col = tn + wc * 64 + j * 16 + lr;
        float v = acc[i][j][r] + bv[j];
        if (MODE == 2) {
          const float u = 0.7978845608028654f * v * (1.0f + 0.044715f * v * v);
          const float t = 1.0f - 2.0f / (__expf(2.0f * u) + 1.0f);
          v = 0.5f * v * (1.0f + t);
        }
        outB[(size_t)row * N + col] = f2bf(v);
      }
}

// ---------------------------------------------------------------------------
// softmax + pack macro (per q-group), S^T layout: lane lr owns q-row iQ.
// ---------------------------------------------------------------------------
#define SOFTMAX_PACK(S, MR, SDQ, ACC, IQ, P2)                                  \
  {                                                                            \
    const float f0 = (float)((IQ) - jt - lg * 4);                              \
    float mt = -1e30f;                                                         \
    _Pragma("unroll")                                                          \
    for (int n = 0; n < 4; n++) {                                              \
      const float fj = f0 - (float)(n * 16);                                   \
      _Pragma("unroll")                                                        \
      for (int r = 0; r < 4; r++) {                                            \
        const float v = fmaf(S[n][r], scl2e, -slope2e * fabsf(fj - (float)r)); \
        S[n][r] = v;                                                           \
        mt = fmaxf(mt, v);                                                     \
      }                                                                        \
    }                                                                          \
    mt = fmaxf(mt, __shfl_xor(mt, 16));                                        \
    mt = fmaxf(mt, __shfl_xor(mt, 32));                                        \
    if (!__all(mt <= MR)) {                                                    \
      const float mN = fmaxf(MR, mt);                                          \
      const float fq = exp2f(MR - mN);                                         \
      MR = mN;                                                                 \
      SDQ *= fq;                                                               \
      float fA[4];                                                             \
      _Pragma("unroll")                                                        \
      for (int r = 0; r < 4; r++) fA[r] = __shfl(fq, lg * 4 + r);              \
      _Pragma("unroll")                                                        \
      for (int n = 0; n < 4; n++)                                              \
        _Pragma("unroll")                                                      \
        for (int r = 0; r < 4; r++) ACC[n][r] *= fA[r];                        \
    }                                                                          \
    float rs = 0.0f;                                                           \
    _Pragma("unroll")                                                          \
    for (int n = 0; n < 4; n++)                                                \
      _Pragma("unroll")                                                        \
      for (int r = 0; r < 4; r++) {                                            \
        const float p = exp2f(S[n][r] - MR);                                   \
        S[n][r] = p;                                                           \
        rs += p;                                                               \
      }                                                                        \
    rs += __shfl_xor(rs, 16);                                                  \
    rs += __shfl_xor(rs, 32);                                                  \
    SDQ += rs;                                                                 \
    _Pragma("unroll")                                                          \
    for (int n = 0; n < 4; n++) {                                              \
      P2[n][0] = cvt_pk_bf16(S[n][0], S[n][1]);                                \
      P2[n][1] = cvt_pk_bf16(S[n][2], S[n][3]);                                \
    }                                                                          \
  }

// ---------------------------------------------------------------------------
// Fused attention v4: QBLK=128, double-buffered K/V LDS (1 barrier/step).
// Per step: barrier -> {ds_write tile s+1 to buf[s^1]  ||  compute tile s
// from buf[s]} -> issue global loads for s+2. Math identical to v3.
// qkv [B*T, 3072] bf16; grid (bh=256, qt=4). In-place q output.
// ---------------------------------------------------------------------------
__global__ __launch_bounds__(256)
void te_attn(uint16_t* __restrict__ qkv)
{
  __shared__ uint16_t kl[2][64 * 64];   // K[j][d] swizzled chunks, dbuf
  __shared__ uint16_t vt[2][64 * 64];   // V^T[d][j] swizzled chunks, dbuf
  const int tid = threadIdx.x;
  const int w = tid >> 6, l = tid & 63;
  const int lr = l & 15, lg = l >> 4;
  const int bh = blockIdx.x, qt = blockIdx.y;   // qt 0..3
  const int h = bh & 15, b = bh >> 4;

  const int iQ0 = qt * 128 + w * 16 + lr;       // group 0; group 1 = +64
  u16x8 qf[2][2];
#pragma unroll
  for (int g = 0; g < 2; g++) {
    const size_t qoff = ((size_t)(b * 512 + iQ0 + g * 64)) * 3072 + h * 64 + lg * 8;
    qf[g][0] = *(const u16x8*)&qkv[qoff];
    qf[g][1] = *(const u16x8*)&qkv[qoff + 32];
  }
  const float LOG2E = 1.4426950408889634f;
  const float scl2e = 0.125f * LOG2E;
  const float slope2e = exp2f(-0.5f * (float)(h + 1)) * LOG2E;

  const int sjb = tid >> 3;           // 0..31 (j within half-tile)
  const int sd0 = (tid & 7) * 8;      // d chunk start

  float mR0 = -1e30f, sdq0 = 0.0f, mR1 = -1e30f, sdq1 = 0.0f;
  f32x4 acc0[4] = {}, acc1[4] = {};

  u16x8 kreg[2], vreg[2];
  auto loadKV = [&](int step) {
    const int jtl = ((qt * 2 + step) & 7) * 64;
#pragma unroll
    for (int cc = 0; cc < 2; cc++) {
      const int j = sjb + cc * 32;
      const size_t rbase = ((size_t)(b * 512 + jtl + j)) * 3072 + h * 64 + sd0;
      kreg[cc] = *(const u16x8*)&qkv[rbase + 1024];
      vreg[cc] = *(const u16x8*)&qkv[rbase + 2048];
    }
  };
  auto writeKV = [&](int buf) {
#pragma unroll
    for (int cc = 0; cc < 2; cc++) {
      const int j = sjb + cc * 32;
      *(u16x8*)&kl[buf][j * 64 + (((sd0 >> 3) ^ (j & 7)) << 3)] = kreg[cc];
      const int cV = (((j >> 3) ^ (sd0 >> 3)) << 3) + (j & 7);
#pragma unroll
      for (int e = 0; e < 8; e++) vt[buf][(sd0 + e) * 64 + cV] = vreg[cc][e];
    }
  };

  // prologue: tile0 -> buf0; tile1 -> regs
  loadKV(0);
  writeKV(0);
  loadKV(1);

  for (int step = 0; step < 8; step++) {
    const int jt = ((qt * 2 + step) & 7) * 64;
    const int cur = step & 1;
    __syncthreads();                 // buf[cur] writes visible; prior reads done
    if (step < 7) {
      writeKV(cur ^ 1);              // stage tile s+1 (overlaps compute below)
      if (step < 6) loadKV(step + 2);
    }

    // ---- S^T = mfma(K, Q) for both q-groups (K-frags shared) ----
    f32x4 s0[4] = {}, s1[4] = {};
#pragma unroll
    for (int kk = 0; kk < 2; kk++) {
      u16x8 kf[4];
#pragma unroll
      for (int n = 0; n < 4; n++) {
        const int row = n * 16 + lr;
        kf[n] = *(const u16x8*)&kl[cur][row * 64 + (((kk * 4 + lg) ^ (lr & 7)) << 3)];
      }
      __builtin_amdgcn_s_setprio(1);
#pragma unroll
      for (int n = 0; n < 4; n++) {
        s0[n] = mfma16(kf[n], qf[0][kk], s0[n]);
        s1[n] = mfma16(kf[n], qf[1][kk], s1[n]);
      }
      __builtin_amdgcn_s_setprio(0);
    }

    // ---- softmax + pack per group ----
    uint32_t P2a[4][2], P2b[4][2];
    SOFTMAX_PACK(s0, mR0, sdq0, acc0, iQ0,      P2a);
    SOFTMAX_PACK(s1, mR1, sdq1, acc1, iQ0 + 64, P2b);

    // ---- redistribute to A-frag layout + PV (V-frags shared) ----
#pragma unroll
    for (int kk = 0; kk < 2; kk++) {
      uint32_t pw0[4], pw1[4];
#pragma unroll
      for (int t = 0; t < 4; t++) {
        const int srcLane = lr + 16 * ((lg & 1) * 2 + (t >> 1));
        const uint32_t a0 = __shfl(P2a[2 * kk + 0][t & 1], srcLane);
        const uint32_t b0 = __shfl(P2a[2 * kk + 1][t & 1], srcLane);
        pw0[t] = (lg >> 1) ? b0 : a0;
        const uint32_t a1 = __shfl(P2b[2 * kk + 0][t & 1], srcLane);
        const uint32_t b1 = __shfl(P2b[2 * kk + 1][t & 1], srcLane);
        pw1[t] = (lg >> 1) ? b1 : a1;
      }
      u32x4 q0 = { pw0[0], pw0[1], pw0[2], pw0[3] };
      u32x4 q1 = { pw1[0], pw1[1], pw1[2], pw1[3] };
      u16x8 pf0 = __builtin_bit_cast(u16x8, q0);
      u16x8 pf1 = __builtin_bit_cast(u16x8, q1);
      u16x8 vf[4];
#pragma unroll
      for (int n = 0; n < 4; n++) {
        const int row = n * 16 + lr;
        vf[n] = *(const u16x8*)&vt[cur][row * 64 + ((((kk * 4 + lg) ^ (2 * n + (lr >> 3))) & 7) << 3)];
      }
      __builtin_amdgcn_s_setprio(1);
#pragma unroll
      for (int n = 0; n < 4; n++) {
        acc0[n] = mfma16(pf0, vf[n], acc0[n]);
        acc1[n] = mfma16(pf1, vf[n], acc1[n]);
      }
      __builtin_amdgcn_s_setprio(0);
    }
  }

  // ---- epilogue: O[i][d] for both groups ----
  {
    float sdA[4];
#pragma unroll
    for (int r = 0; r < 4; r++) sdA[r] = 1.0f / __shfl(sdq0, lg * 4 + r);
#pragma unroll
    for (int n = 0; n < 4; n++)
#pragma unroll
      for (int r = 0; r < 4; r++) {
        const int i = qt * 128 + w * 16 + lg * 4 + r;
        const int d = h * 64 + n * 16 + lr;
        qkv[((size_t)(b * 512 + i)) * 3072 + d] = f2bf(acc0[n][r] * sdA[r]);
      }
  }
  {
    float sdA[4];
#pragma unroll
    for (int r = 0; r < 4; r++) sdA[r] = 1.0f / __shfl(sdq1, lg * 4 + r);
#pragma unroll
    for (int n = 0; n < 4; n++)
#pragma unroll
      for (int r = 0; r < 4; r++) {
        const int i = qt * 128 + 64 + w * 16 + lg * 4 + r;
        const int d = h * 64 + n * 16 + lr;
        qkv[((size_t)(b * 512 + i)) * 3072 + d] = f2bf(acc1[n][r] * sdA[r]);
      }
  }
}

// ---------------------------------------------------------------------------
// LN (bf16 residual): x = h(bf16) + delta(bf16) in f32; y = LN(x)*w + b.
// FINAL=0: writes hout (bf16, aliases h).  FINAL=1: writes fout (f32 d_out).
// ---------------------------------------------------------------------------
template<int FINAL>
__global__ __launch_bounds__(256)
void te_ln(const uint16_t* __restrict__ h, const uint16_t* __restrict__ delta,
           const float* __restrict__ w, const float* __restrict__ b,
           uint16_t* __restrict__ hout, float* __restrict__ fout)
{
  const int row = blockIdx.x, t = threadIdx.x;
  const size_t base = (size_t)row * 1024 + t * 4;
  u16x4 hv = *(const u16x4*)&h[base];
  u16x4 dv = *(const u16x4*)&delta[base];
  float x[4];
#pragma unroll
  for (int i = 0; i < 4; i++) x[i] = bf2f(hv[i]) + bf2f(dv[i]);
  float s = x[0] + x[1] + x[2] + x[3];
  float ss = x[0]*x[0] + x[1]*x[1] + x[2]*x[2] + x[3]*x[3];
#pragma unroll
  for (int msk = 32; msk >= 1; msk >>= 1) {
    s  += __shfl_xor(s, msk);
    ss += __shfl_xor(ss, msk);
  }
  __shared__ float rs[4], rq[4];
  const int wv = t >> 6;
  if ((t & 63) == 0) { rs[wv] = s; rq[wv] = ss; }
  __syncthreads();
  s  = rs[0] + rs[1] + rs[2] + rs[3];
  ss = rq[0] + rq[1] + rq[2] + rq[3];
  const float mean = s * (1.0f / 1024.0f);
  const float var  = ss * (1.0f / 1024.0f) - mean * mean;
  const float rstd = rsqrtf(var + 1e-5f);
  f32x4 wv4 = *(const f32x4*)&w[t * 4];
  f32x4 bv4 = *(const f32x4*)&b[t * 4];
  if (FINAL == 0) {
    u16x4 bo;
#pragma unroll
    for (int i = 0; i < 4; i++)
      bo[i] = f2bf((x[i] - mean) * rstd * wv4[i] + bv4[i]);
    *(u16x4*)&hout[base] = bo;
  } else {
    f32x4 yo;
#pragma unroll
    for (int i = 0; i < 4; i++)
      yo[i] = (x[i] - mean) * rstd * wv4[i] + bv4[i];
    *(f32x4*)&fout[base] = yo;
  }
}

// ---------------------------------------------------------------------------
extern "C" void kernel_launch(void* const* d_in, const int* in_sizes, int n_in,
                              void* d_out, int out_size, void* d_ws, size_t ws_size,
                              hipStream_t stream)
{
  (void)in_sizes; (void)n_in; (void)out_size; (void)ws_size;
  const float* x     = (const float*)d_in[0];
  const float* bn_w  = (const float*)d_in[1];
  const float* bn_b  = (const float*)d_in[2];
  const float* qkv_w = (const float*)d_in[3];
  const float* qkv_b = (const float*)d_in[4];
  const float* out_w = (const float*)d_in[5];
  const float* out_b = (const float*)d_in[6];
  const float* ln1_w = (const float*)d_in[7];
  const float* ln1_b = (const float*)d_in[8];
  const float* ln2_w = (const float*)d_in[9];
  const float* ln2_b = (const float*)d_in[10];
  const float* ff1_w = (const float*)d_in[11];
  const float* ff1_b = (const float*)d_in[12];
  const float* ff2_w = (const float*)d_in[13];
  const float* ff2_b = (const float*)d_in[14];

  char* ws = (char*)d_ws;
  uint16_t* h_bf    = (uint16_t*)ws;                      // 16 MiB @ 0
  uint16_t* qkvb    = (uint16_t*)(ws + (16u  << 20));     // 48 MiB @ 16
  uint16_t* scrA    = (uint16_t*)(ws + (64u  << 20));     // 16 MiB @ 64 (also x_bf)
  uint16_t* qkvw_bf = (uint16_t*)(ws + (80u  << 20));     // 36 MiB @ 80
  uint16_t* ff2w_bf = (uint16_t*)(ws + (116u << 20));     // 12 MiB @ 116
  uint16_t* bnw_bf  = (uint16_t*)(ws + (128u << 20));     //  2 MiB @ 128 (130 total)
  // d_out as scratch for weights that die before the final LN writes d_out:
  uint16_t* outw_bf = (uint16_t*)d_out;                   // 12 MiB @ 0
  uint16_t* ff1w_bf = (uint16_t*)((char*)d_out + (12u << 20)); // 12 MiB @ 12
  float*    outf    = (float*)d_out;                      // final fp32 output

  dim3 blk(256);
  dim3 blk512(512);

  // one-time fp32 -> bf16 conversions (weights + x), single launch
  te_cvt_all<<<dim3(23040), blk, 0, stream>>>(qkv_w, out_w, ff1_w, ff2_w, bn_w, x,
                                              qkvw_bf, outw_bf, ff1w_bf, ff2w_bf,
                                              bnw_bf, scrA);

  // bottleneck: h0 = x @ bn_w^T + bn_b  (bf16 residual)
  te_gemm256<0><<<dim3(256), blk512, 0, stream>>>(scrA, 1024, bnw_bf, bn_b,
                                                  h_bf, 1024, 1024);

  for (int l = 0; l < 6; l++) {
    te_gemm256<0><<<dim3(768), blk512, 0, stream>>>(
        h_bf, 1024, qkvw_bf + (size_t)l * 3072 * 1024, qkv_b + l * 3072,
        qkvb, 3072, 1024);
    te_attn<<<dim3(256, 4), blk, 0, stream>>>(qkvb);
    te_gemm256<0><<<dim3(256), blk512, 0, stream>>>(
        qkvb, 3072, outw_bf + (size_t)l * 1024 * 1024, out_b + l * 1024,
        scrA, 1024, 1024);
    te_ln<0><<<dim3(8192), blk, 0, stream>>>(h_bf, scrA, ln1_w + l * 1024, ln1_b + l * 1024,
                                             h_bf, nullptr);
    te_gemm256<2><<<dim3(256), blk512, 0, stream>>>(
        h_bf, 1024, ff1w_bf + (size_t)l * 1024 * 1024, ff1_b + l * 1024,
        scrA, 1024, 1024);
    te_gemm256<0><<<dim3(256), blk512, 0, stream>>>(
        scrA, 1024, ff2w_bf + (size_t)l * 1024 * 1024, ff2_b + l * 1024,
        qkvb, 1024, 1024);
    if (l == 5) {
      te_ln<1><<<dim3(8192), blk, 0, stream>>>(h_bf, qkvb, ln2_w + l * 1024, ln2_b + l * 1024,
                                               nullptr, outf);
    } else {
      te_ln<0><<<dim3(8192), blk, 0, stream>>>(h_bf, qkvb, ln2_w + l * 1024, ln2_b + l * 1024,
                                               h_bf, nullptr);
    }
  }
}